// Round 15
// baseline (745.728 us; speedup 1.0000x reference)
//
#include <hip/hip_runtime.h>
#include <math.h>

// Problem constants
#define B_   4096
#define T_   193
#define D_   50
#define H_   50
#define V_   11
#define BT   16                    // batch rows per block (= per compute wave)
#define NBLK (B_ / BT)             // 256 blocks = 1 block/CU
#define CH   12                    // timesteps per LDS chunk (double-buffered)
#define NCH  ((T_ + CH - 1) / CH)  // 17 chunks (16 full + L=1 tail)
#define NTHREADS 256               // wave 0: compute; waves 1-3: staging
#define NT_  13                    // gate tiles (200 rows -> 13 x 16)

typedef __bf16 bf16x8 __attribute__((ext_vector_type(8)));
typedef float  f32x4  __attribute__((ext_vector_type(4)));

__device__ __forceinline__ float sigf(float v) { return 1.0f / (1.0f + __expf(-v)); }
__device__ __forceinline__ float thf(float v)  { return 2.0f / (1.0f + __expf(-2.0f * v)) - 1.0f; }

// R14: BATCH-PARALLEL decomposition. R7..R13 (gate-parallel) all stall at
// ~2240 cyc/step: the per-step s_barrier phase-locks 13 waves (convoy), and
// multi-block "fixes" double total work (R5/R13 lesson). Here ONE wave owns
// its 16 batch cols END TO END: it computes all 13 gate tiles and h never
// leaves the wave (LDS round-trip ordered by lgkmcnt, compiler-enforced) --
// ZERO barriers in the 193-step loop. Waves 1-3 are pure x-staging
// producers, synced once per 12-step chunk.
// Precision: h stored hi+lo bf16 (exact to 2^-16), Whh hi+lo (exact), bias
// rides k=63 vs constant-1.0 slot; Wih hi-only + x bf16 = two 2^-9 sources.
// Weights resident in VGPRs (13 tiles x 6 frags = 312); __launch_bounds__
// (256,1) caps at 512 -- spill tripwire is WRITE_SIZE.
__global__ __launch_bounds__(NTHREADS, 1) void lstm_bp_kernel(
    const float* __restrict__ x,      // [B, T, D]
    const float* __restrict__ W_ih,   // [200, 50]
    const float* __restrict__ W_hh,   // [200, 50]
    const float* __restrict__ b_ih,   // [200]
    const float* __restrict__ b_hh,   // [200]
    const float* __restrict__ fc_w,   // [11, 50]
    const float* __restrict__ fc_b,   // [11]
    float* __restrict__ out)          // [B, 11]
{
    // xs: 2 chunk buffers of [tc][s][lane][8 bf16] fragments. 2 x 24 KB
    __shared__ __align__(16) unsigned short xs[2 * CH * 128 * 8];
    // hb: SINGLE buffer, 4 sets (hi-k2 | hi-k3 | lo-k2 | lo-k3) x [64][8]. 4 KB
    __shared__ __align__(16) unsigned short hb[4 * 64 * 8];
    __shared__ float hfin[BT * 53];
    __shared__ float lgts[BT][V_];

    const int tid  = threadIdx.x;
    const int wid  = tid >> 6;
    const int lane = tid & 63;
    const int n    = lane & 15;   // batch col
    const int kg   = lane >> 4;   // k-group
    const int row0 = blockIdx.x * BT;

    // ---- init hb (256 int4 = 4KB) + bias slot ----
    {
        int4 z; z.x = 0; z.y = 0; z.z = 0; z.w = 0;
        reinterpret_cast<int4*>(hb)[tid] = z;
    }
    __syncthreads();   // bias write must not race the zeroing
    if (tid < 16) {
        // bias u=63: set 1 (hi,k3), frag-lane 48+n, j=7 ; bf16(1.0)
        hb[512 + (48 + tid) * 8 + 7] = 0x3F80;
    }

    // ---- staging lambda (waves 1-3; 192 threads) ----
    const int stid = tid - 64;
    auto stageChunk = [&](int cc, int buf) {
        const int t0 = cc * CH;
        const int L  = (T_ - t0 < CH) ? (T_ - t0) : CH;
        const int nfrag = L * 128;
        #pragma unroll
        for (int i = 0; i < 8; ++i) {           // 8*192 = 1536 = CH*128
            const int fi = stid + i * 192;
            if (fi < nfrag) {
                const int tc  = fi >> 7;
                const int rem = fi & 127;
                const int s   = rem >> 6;
                const int l   = rem & 63;
                const int nn  = l & 15;
                const int kk  = l >> 4;
                const float* base = x + ((size_t)(row0 + nn) * T_ + (t0 + tc)) * D_;
                float2 v[4];
                #pragma unroll
                for (int j = 0; j < 4; ++j) {
                    int col = 32 * s + kk * 8 + 2 * j;
                    if (col > 48) col = 48;     // clamp: garbage * 0-weight
                    v[j] = *reinterpret_cast<const float2*>(base + col);
                }
                bf16x8 w;
                #pragma unroll
                for (int j = 0; j < 4; ++j) {
                    w[2 * j]     = (__bf16)v[j].x;
                    w[2 * j + 1] = (__bf16)v[j].y;
                }
                reinterpret_cast<int4*>(xs)[buf * (CH * 128) + fi] =
                    __builtin_bit_cast(int4, w);
            }
        }
    };

    // ---- compute wave: resident weight fragments (13 tiles) ----
    // Wih hi only (2 frags/tile); Whh hi+lo (4 frags/tile). 312 VGPR.
    bf16x8 wxh[NT_][2], whh[NT_][2], whl[NT_][2];
    if (wid == 0) {
        #pragma unroll
        for (int t = 0; t < NT_; ++t) {
            const int gp = 16 * t + n;     // g' = 4*j + q gate interleave
            const int q  = gp & 3;
            const int ju = gp >> 2;
            const bool real = (ju < 50);
            const int row = real ? (q * 50 + ju) : 0;
            #pragma unroll
            for (int s = 0; s < 2; ++s) {
                bf16x8 xh, hh, hl;
                #pragma unroll
                for (int j = 0; j < 8; ++j) {
                    const int k = s * 32 + kg * 8 + j;
                    float vx = 0.0f, vh = 0.0f;
                    if (real) {
                        if (k < 50) { vx = W_ih[row * 50 + k]; vh = W_hh[row * 50 + k]; }
                        if (k == 63) vh = b_ih[row] + b_hh[row];
                    }
                    const __bf16 hhi = (__bf16)vh;
                    xh[j] = (__bf16)vx;
                    hh[j] = hhi;
                    hl[j] = (__bf16)(vh - (float)hhi);
                }
                wxh[t][s] = xh; whh[t][s] = hh; whl[t][s] = hl;
            }
        }
    } else {
        stageChunk(0, 0);   // stage chunk 0 while wave 0 loads weights
    }
    __syncthreads();

    float cst[NT_];
    #pragma unroll
    for (int t = 0; t < NT_; ++t) cst[t] = 0.0f;
    const f32x4 zz = {0.0f, 0.0f, 0.0f, 0.0f};
    const int4* hbv = reinterpret_cast<const int4*>(hb);

    #pragma unroll 1
    for (int c = 0; c < NCH; ++c) {
        if (wid == 0) {
            const int4* xb = reinterpret_cast<const int4*>(xs) + (c & 1) * (CH * 128);
            const int L = (T_ - c * CH < CH) ? (T_ - c * CH) : CH;
            #pragma unroll 1
            for (int tc = 0; tc < L; ++tc) {
                // x fragments (chunk-stable) + h fragments (own writes, lgkm-ordered)
                const bf16x8 bx0 = __builtin_bit_cast(bf16x8, xb[tc * 128 + lane]);
                const bf16x8 bx1 = __builtin_bit_cast(bf16x8, xb[tc * 128 + 64 + lane]);
                const bf16x8 bh0 = __builtin_bit_cast(bf16x8, hbv[lane]);
                const bf16x8 bh1 = __builtin_bit_cast(bf16x8, hbv[64 + lane]);
                const bf16x8 bl0 = __builtin_bit_cast(bf16x8, hbv[128 + lane]);
                const bf16x8 bl1 = __builtin_bit_cast(bf16x8, hbv[192 + lane]);
                const bool last = (c * CH + tc == T_ - 1);

                #pragma unroll
                for (int t = 0; t < NT_; ++t) {
                    // x-projection (2) then split h-chains (3+3), a = c1+c2
                    f32x4 ax = __builtin_amdgcn_mfma_f32_16x16x32_bf16(wxh[t][0], bx0, zz, 0, 0, 0);
                    ax = __builtin_amdgcn_mfma_f32_16x16x32_bf16(wxh[t][1], bx1, ax, 0, 0, 0);
                    f32x4 c1 = __builtin_amdgcn_mfma_f32_16x16x32_bf16(whh[t][0], bh0, ax, 0, 0, 0);
                    f32x4 c2 = __builtin_amdgcn_mfma_f32_16x16x32_bf16(whh[t][0], bl0, zz, 0, 0, 0);
                    c1 = __builtin_amdgcn_mfma_f32_16x16x32_bf16(whh[t][1], bh1, c1, 0, 0, 0);
                    c2 = __builtin_amdgcn_mfma_f32_16x16x32_bf16(whh[t][1], bl1, c2, 0, 0, 0);
                    c1 = __builtin_amdgcn_mfma_f32_16x16x32_bf16(whl[t][0], bh0, c1, 0, 0, 0);
                    c2 = __builtin_amdgcn_mfma_f32_16x16x32_bf16(whl[t][1], bh1, c2, 0, 0, 0);
                    const f32x4 a = c1 + c2;

                    const float ii = sigf(a[0]);
                    const float ff = sigf(a[1]);
                    const float g2 = thf(a[2]);
                    const float oo = sigf(a[3]);
                    cst[t] = fmaf(ff, cst[t], ii * g2);
                    const float h = oo * thf(cst[t]);

                    const __bf16 hhi = (__bf16)h;
                    const __bf16 hlo = (__bf16)(h - (float)hhi);
                    const int u  = 4 * t + kg;
                    const int ho = (u >> 5) * 512 + ((((u & 31) >> 3) << 4) | n) * 8 + (u & 7);
                    hb[ho]        = __builtin_bit_cast(unsigned short, hhi);
                    hb[1024 + ho] = __builtin_bit_cast(unsigned short, hlo);
                    if (last && u < 50) hfin[n * 53 + u] = h;
                }
            }
        } else {
            if (c + 1 < NCH) stageChunk(c + 1, (c + 1) & 1);
        }
        __syncthreads();   // one barrier per 12-step chunk (17 total)
    }

    // ---- FC head + log_softmax ----
    if (tid < BT * V_) {
        const int bn = tid / V_;
        const int v  = tid % V_;
        float a = fc_b[v];
        #pragma unroll
        for (int j = 0; j < 50; ++j) {
            float hj = hfin[bn * 53 + j];
            hj = hj > 0.0f ? hj : 0.0f;
            a = fmaf(hj, fc_w[v * 50 + j], a);
        }
        lgts[bn][v] = a;
    }
    __syncthreads();
    if (tid < BT * V_) {
        const int bn = tid / V_;
        const int v  = tid % V_;
        float m = -1e30f;
        #pragma unroll
        for (int u = 0; u < V_; ++u) m = fmaxf(m, lgts[bn][u]);
        float s = 0.0f;
        #pragma unroll
        for (int u = 0; u < V_; ++u) s += __expf(lgts[bn][u] - m);
        out[(size_t)(row0 + bn) * V_ + v] = lgts[bn][v] - m - __logf(s);
    }
}

extern "C" void kernel_launch(void* const* d_in, const int* in_sizes, int n_in,
                              void* d_out, int out_size, void* d_ws, size_t ws_size,
                              hipStream_t stream) {
    const float* x    = (const float*)d_in[0];
    const float* W_ih = (const float*)d_in[1];
    const float* W_hh = (const float*)d_in[2];
    const float* b_ih = (const float*)d_in[3];
    const float* b_hh = (const float*)d_in[4];
    const float* fc_w = (const float*)d_in[5];
    const float* fc_b = (const float*)d_in[6];
    float* out = (float*)d_out;

    lstm_bp_kernel<<<NBLK, NTHREADS, 0, stream>>>(
        x, W_ih, W_hh, b_ih, b_hh, fc_w, fc_b, out);
}

// Round 16
// 214.583 us; speedup vs baseline: 3.4752x; 3.4752x over previous
//
#include <hip/hip_runtime.h>
#include <math.h>

// Problem constants
#define B_   4096
#define T_   193
#define D_   50
#define H_   50
#define V_   11
#define BT   16                    // batch rows per block
#define NBLK (B_ / BT)             // 256 blocks = 1 block/CU
#define CH   16                    // timesteps per LDS chunk (double-buffered)
#define NCH  ((T_ + CH - 1) / CH)  // 13 chunks (12 full + L=1 tail)
#define NTHREADS 832               // 13 waves, ONE gate-tile per wave
#define NP   3                     // staging frags/thread (832*3 >= 16*128)

typedef __bf16 bf16x8 __attribute__((ext_vector_type(8)));
typedef float  f32x4  __attribute__((ext_vector_type(4)));

__device__ __forceinline__ float sigf(float v) { return 1.0f / (1.0f + __expf(-v)); }
__device__ __forceinline__ float thf(float v)  { return 2.0f / (1.0f + __expf(-2.0f * v)) - 1.0f; }

// LDS-only barrier: leaves global loads in flight (unlike __syncthreads'
// vmcnt(0) drain) so the async next-chunk x prefetch survives step barriers.
__device__ __forceinline__ void lgkm_barrier() {
    asm volatile("s_waitcnt lgkmcnt(0)\n\ts_barrier" ::: "memory");
}

// R15 = R12 with the post-barrier dependency chain cut from depth 3 to 2.
// Evidence: the only knob that moves the wall across R7..R14 is post-barrier
// chain depth (R7 depth-2 = 180us; R12 depth-3 = 218us). Same MFMA count and
// identical arithmetic terms as R12 (absmax 0.0156), but reassociated into
// THREE independent depth-2 chains:
//   pre-barrier:  ax1 = wxh0*x0 -> wxl0*x0 ; ax2 = wxh1*x1 -> wxl1*x1
//   post-barrier: c1 = whh0*bh0 -> whh1*bh1   (seed ax1)
//                 c2 = whh0*bl0 -> whh1*bl1   (seed ax2)
//                 c3 = whl0*bh0 -> whl1*bh1   (seed 0)
//   a = (c1 + c2) + c3
// Precision design unchanged: W=W_hi+W_lo, h stored hi+lo, bias at k=63 vs
// constant-1.0 slot; only x->bf16 quantization remains. Init fixes retained.
__global__ __launch_bounds__(NTHREADS) void lstm_mfma_kernel(
    const float* __restrict__ x,      // [B, T, D]
    const float* __restrict__ W_ih,   // [200, 50]
    const float* __restrict__ W_hh,   // [200, 50]
    const float* __restrict__ b_ih,   // [200]
    const float* __restrict__ b_hh,   // [200]
    const float* __restrict__ fc_w,   // [11, 50]
    const float* __restrict__ fc_b,   // [11]
    float* __restrict__ out)          // [B, 11]
{
    // xs: 2 chunk buffers of [tc][s][lane][8 bf16] fragments. 2 x 32 KB
    __shared__ __align__(16) unsigned short xs[2 * CH * 2 * 64 * 8];
    // hb: 2 bufs x 4 sets (h_hi k0 | h_hi k1 | h_lo k0 | h_lo k1) x [64][8]. 8 KB
    __shared__ __align__(16) unsigned short hb[2 * 4 * 64 * 8];
    __shared__ float hfin[BT * 53];
    __shared__ float lgts[BT][V_];

    const int tid  = threadIdx.x;
    const int wid  = tid >> 6;
    const int lane = tid & 63;
    const int n    = lane & 15;   // A-row within tile / B batch col
    const int kg   = lane >> 4;   // k-group
    const int row0 = blockIdx.x * BT;
    const int tile = wid;         // one 16-row gate tile per wave (0..12)

    // ---- init hb: zero ALL 512 int4 (both bufs, hi+lo sets) ----
    {
        int4 z; z.x = 0; z.y = 0; z.z = 0; z.w = 0;
        if (tid < 512) reinterpret_cast<int4*>(hb)[tid] = z;
    }
    __syncthreads();   // bias write must not race the zeroing
    if (tid < 32) {
        // bias slot u=63 (h_hi, set 1, lane 48+n, j=7) of buf (tid>>4)
        hb[(tid >> 4) * 2048 + 512 + (48 + (tid & 15)) * 8 + 7] = 0x3F80;
    }

    // ---- this wave's weight fragments, hi+lo ----
    // x-part ksteps 0,1 (k in [0,64)): W_ih cols; h-part ksteps 0,1: W_hh
    // cols (k<50), bias at k=63.
    bf16x8 wxh[2], wxl[2], whh[2], whl[2];
    {
        const int gp = 16 * tile + n;  // g' (gate-interleaved row: 4*j + q)
        const int q  = gp & 3;
        const int ju = gp >> 2;
        const bool real = (ju < 50);
        const int row = real ? (q * 50 + ju) : 0;
        #pragma unroll
        for (int s = 0; s < 2; ++s) {
            bf16x8 xh, xl, hh, hl;
            #pragma unroll
            for (int j = 0; j < 8; ++j) {
                const int k = s * 32 + kg * 8 + j;
                float vx = 0.0f, vh = 0.0f;
                if (real) {
                    if (k < 50) { vx = W_ih[row * 50 + k]; vh = W_hh[row * 50 + k]; }
                    if (k == 63) vh = b_ih[row] + b_hh[row];
                }
                const __bf16 xhi = (__bf16)vx;
                const __bf16 hhi = (__bf16)vh;
                xh[j] = xhi; xl[j] = (__bf16)(vx - (float)xhi);
                hh[j] = hhi; hl[j] = (__bf16)(vh - (float)hhi);
            }
            wxh[s] = xh; wxl[s] = xl; whh[s] = hh; whl[s] = hl;
        }
    }

    // h LDS write offset within the hi region (lo = +1024); u = hidden unit
    const int u_   = 4 * tile + kg;
    const int hoff = (u_ >> 5) * 512 + ((((u_ & 31) >> 3) << 4) | n) * 8 + (u_ & 7);

    // ---- chunk staging: global->regs (async) then regs->LDS bf16 frags ----
    float2 P[NP][4];   // 24 VGPRs; static indexing only (full unroll)

    auto loadChunk = [&](int c) {
        const int t0 = c * CH;
        const int L  = (T_ - t0 < CH) ? (T_ - t0) : CH;
        const int nfrag = L * 128;
        #pragma unroll
        for (int i = 0; i < NP; ++i) {
            const int fi = tid + i * NTHREADS;
            if (fi < nfrag) {
                const int tc  = fi >> 7;
                const int rem = fi & 127;
                const int s   = rem >> 6;
                const int l   = rem & 63;
                const int nn  = l & 15;
                const int kk  = l >> 4;
                const float* base = x + ((size_t)(row0 + nn) * T_ + (t0 + tc)) * D_;
                #pragma unroll
                for (int j = 0; j < 4; ++j) {
                    int col = 32 * s + kk * 8 + 2 * j;
                    if (col > 48) col = 48;   // clamp: finite garbage * 0-weight
                    P[i][j] = *reinterpret_cast<const float2*>(base + col);
                }
            }
        }
    };
    auto writeChunk = [&](int c, int b) {
        const int t0 = c * CH;
        const int L  = (T_ - t0 < CH) ? (T_ - t0) : CH;
        const int nfrag = L * 128;
        #pragma unroll
        for (int i = 0; i < NP; ++i) {
            const int fi = tid + i * NTHREADS;
            if (fi < nfrag) {
                bf16x8 w;
                #pragma unroll
                for (int j = 0; j < 4; ++j) {
                    w[2 * j]     = (__bf16)P[i][j].x;
                    w[2 * j + 1] = (__bf16)P[i][j].y;
                }
                reinterpret_cast<int4*>(xs)[b * (CH * 128) + fi] =
                    __builtin_bit_cast(int4, w);
            }
        }
    };

    loadChunk(0);
    writeChunk(0, 0);
    __syncthreads();        // one full (vmcnt) drain for chunk 0
    loadChunk(1);           // chunk 1 flies during chunk 0's 16 steps

    float cst = 0.0f;
    float hlast = 0.0f;
    const f32x4 zz = {0.0f, 0.0f, 0.0f, 0.0f};
    f32x4 ax1, ax2;
    const int4* xsv = reinterpret_cast<const int4*>(xs);
    const int4* hbv = reinterpret_cast<const int4*>(hb);  // 256 int4 per buf

// x-projection: TWO independent depth-2 chains (pre-barrier slack)
#define XPROJ(X0, X1)                                                         \
    {                                                                         \
        ax1 = __builtin_amdgcn_mfma_f32_16x16x32_bf16(wxh[0], (X0), zz, 0, 0, 0);  \
        ax2 = __builtin_amdgcn_mfma_f32_16x16x32_bf16(wxh[1], (X1), zz, 0, 0, 0);  \
        ax1 = __builtin_amdgcn_mfma_f32_16x16x32_bf16(wxl[0], (X0), ax1, 0, 0, 0); \
        ax2 = __builtin_amdgcn_mfma_f32_16x16x32_bf16(wxl[1], (X1), ax2, 0, 0, 0); \
    }

// One LSTM step. CUR/TC literal after unroll. LAST=1: stage next chunk
// instead of projecting next x. Three parallel depth-2 h-chains.
#define STEP(CUR, TC, LAST)                                                   \
    {                                                                         \
        const int4* hc = hbv + (CUR) * 256;                                   \
        const bf16x8 bh0 = __builtin_bit_cast(bf16x8, hc[lane]);              \
        const bf16x8 bh1 = __builtin_bit_cast(bf16x8, hc[64 + lane]);         \
        const bf16x8 bl0 = __builtin_bit_cast(bf16x8, hc[128 + lane]);        \
        const bf16x8 bl1 = __builtin_bit_cast(bf16x8, hc[192 + lane]);        \
        f32x4 c1 = __builtin_amdgcn_mfma_f32_16x16x32_bf16(whh[0], bh0, ax1, 0, 0, 0); \
        f32x4 c3 = __builtin_amdgcn_mfma_f32_16x16x32_bf16(whl[0], bh0, zz, 0, 0, 0);  \
        f32x4 c2 = __builtin_amdgcn_mfma_f32_16x16x32_bf16(whh[0], bl0, ax2, 0, 0, 0); \
        c1 = __builtin_amdgcn_mfma_f32_16x16x32_bf16(whh[1], bh1, c1, 0, 0, 0);        \
        c3 = __builtin_amdgcn_mfma_f32_16x16x32_bf16(whl[1], bh1, c3, 0, 0, 0);        \
        c2 = __builtin_amdgcn_mfma_f32_16x16x32_bf16(whh[1], bl1, c2, 0, 0, 0);        \
        const f32x4 a = (c1 + c2) + c3;                                       \
        const float ii = sigf(a[0]);                                          \
        const float ff = sigf(a[1]);                                          \
        const float g2 = thf(a[2]);                                           \
        const float oo = sigf(a[3]);                                          \
        cst = fmaf(ff, cst, ii * g2);                                         \
        const float h = oo * thf(cst);                                        \
        hlast = h;                                                            \
        const __bf16 hhi = (__bf16)h;                                         \
        const __bf16 hlo = (__bf16)(h - (float)hhi);                          \
        unsigned short* hw = hb + ((CUR) ^ 1) * 2048;                         \
        hw[hoff]        = __builtin_bit_cast(unsigned short, hhi);            \
        hw[1024 + hoff] = __builtin_bit_cast(unsigned short, hlo);            \
        if (!(LAST)) {                                                        \
            const bf16x8 nx0 = __builtin_bit_cast(                            \
                bf16x8, xb[((TC) + 1) * 128 + lane]);                         \
            const bf16x8 nx1 = __builtin_bit_cast(                            \
                bf16x8, xb[((TC) + 1) * 128 + 64 + lane]);                    \
            XPROJ(nx0, nx1);                                                  \
        } else {                                                              \
            writeChunk(c + 1, bb ^ 1);                                        \
            if (c + 2 < NCH) loadChunk(c + 2);                                \
        }                                                                     \
        lgkm_barrier();                                                       \
    }

    for (int c = 0; c < NCH - 1; ++c) {     // 12 full chunks; cur=0 at entry
        const int bb = c & 1;
        const int4* xb = xsv + bb * (CH * 128);

        // x-projection for step 0 of this chunk
        {
            const bf16x8 x0 = __builtin_bit_cast(bf16x8, xb[lane]);
            const bf16x8 x1 = __builtin_bit_cast(bf16x8, xb[64 + lane]);
            XPROJ(x0, x1);
        }
        #pragma unroll
        for (int p = 0; p < 8; ++p) {
            STEP(0, 2 * p, 0);
            STEP(1, 2 * p + 1, (2 * p + 1 == CH - 1));
        }
        // 16 flips -> cur back to 0 at next chunk entry
    }

    // ---- tail chunk (c = 12, L = 1, cur = 0): step t = 192 ----
    {
        const int4* xb = xsv;   // buf 0 (12 & 1 == 0)
        const bf16x8 x0 = __builtin_bit_cast(bf16x8, xb[lane]);
        const bf16x8 x1 = __builtin_bit_cast(bf16x8, xb[64 + lane]);
        XPROJ(x0, x1);

        const bf16x8 bh0 = __builtin_bit_cast(bf16x8, hbv[lane]);
        const bf16x8 bh1 = __builtin_bit_cast(bf16x8, hbv[64 + lane]);
        const bf16x8 bl0 = __builtin_bit_cast(bf16x8, hbv[128 + lane]);
        const bf16x8 bl1 = __builtin_bit_cast(bf16x8, hbv[192 + lane]);
        f32x4 c1 = __builtin_amdgcn_mfma_f32_16x16x32_bf16(whh[0], bh0, ax1, 0, 0, 0);
        f32x4 c3 = __builtin_amdgcn_mfma_f32_16x16x32_bf16(whl[0], bh0, zz, 0, 0, 0);
        f32x4 c2 = __builtin_amdgcn_mfma_f32_16x16x32_bf16(whh[0], bl0, ax2, 0, 0, 0);
        c1 = __builtin_amdgcn_mfma_f32_16x16x32_bf16(whh[1], bh1, c1, 0, 0, 0);
        c3 = __builtin_amdgcn_mfma_f32_16x16x32_bf16(whl[1], bh1, c3, 0, 0, 0);
        c2 = __builtin_amdgcn_mfma_f32_16x16x32_bf16(whh[1], bl1, c2, 0, 0, 0);
        const f32x4 a = (c1 + c2) + c3;

        cst = fmaf(sigf(a[1]), cst, sigf(a[0]) * thf(a[2]));
        hlast = sigf(a[3]) * thf(cst);
    }

    if (u_ < 50) hfin[n * 53 + u_] = hlast;
    __syncthreads();

    // ---- FC head + log_softmax ----
    if (tid < BT * V_) {
        const int bn = tid / V_;
        const int v  = tid % V_;
        float a = fc_b[v];
        #pragma unroll
        for (int j = 0; j < 50; ++j) {
            float hj = hfin[bn * 53 + j];
            hj = hj > 0.0f ? hj : 0.0f;
            a = fmaf(hj, fc_w[v * 50 + j], a);
        }
        lgts[bn][v] = a;
    }
    __syncthreads();
    if (tid < BT * V_) {
        const int bn = tid / V_;
        const int v  = tid % V_;
        float m = -1e30f;
        #pragma unroll
        for (int u = 0; u < V_; ++u) m = fmaxf(m, lgts[bn][u]);
        float s = 0.0f;
        #pragma unroll
        for (int u = 0; u < V_; ++u) s += __expf(lgts[bn][u] - m);
        out[(size_t)(row0 + bn) * V_ + v] = lgts[bn][v] - m - __logf(s);
    }
}

extern "C" void kernel_launch(void* const* d_in, const int* in_sizes, int n_in,
                              void* d_out, int out_size, void* d_ws, size_t ws_size,
                              hipStream_t stream) {
    const float* x    = (const float*)d_in[0];
    const float* W_ih = (const float*)d_in[1];
    const float* W_hh = (const float*)d_in[2];
    const float* b_ih = (const float*)d_in[3];
    const float* b_hh = (const float*)d_in[4];
    const float* fc_w = (const float*)d_in[5];
    const float* fc_b = (const float*)d_in[6];
    float* out = (float*)d_out;

    lstm_mfma_kernel<<<NBLK, NTHREADS, 0, stream>>>(
        x, W_ih, W_hh, b_ih, b_hh, fc_w, fc_b, out);
}